// Round 4
// baseline (784.231 us; speedup 1.0000x reference)
//
#include <hip/hip_runtime.h>
#include <math.h>

typedef unsigned int u32;
typedef unsigned long long u64;

#define BB 4
#define AA 262144              // 1<<18
#define NN (BB*AA)
#define PRE 4000
#define POST 1000
#define CAP 4096
#define MASKW 64
#define NBLK 63                // ceil(4000/64)

// ---- workspace layout (bytes) ----
static const size_t OFF_HIST = 0;                          // 4*4*256*4 = 16384
static const size_t OFF_PFX  = 16384;                      // u32[4]
static const size_t OFF_NEED = 16448;                      // int[4]
static const size_t OFF_KEPT = 16512;                      // int[4]
static const size_t OFF_CNTG = 16640;                      // int, stride 32 ints (128B) x4
static const size_t OFF_CNTE = 17152;                      // int, stride 32 ints (128B) x4
static const size_t CTRL_END = 17664;
static const size_t OFF_MONO = 17664;                              // u32[NN] = 4 MiB
static const size_t OFF_KEYS = OFF_MONO + (size_t)NN*4;            // u64[4][4096]
static const size_t OFF_SIDX = OFF_KEYS + (size_t)BB*CAP*8;        // int[4][4096]
static const size_t OFF_SSC  = OFF_SIDX + (size_t)BB*CAP*4;        // float[4][4096]
static const size_t OFF_CROW = OFF_SSC  + (size_t)BB*CAP*4;        // float[4][4096][8]
static const size_t OFF_NBOX = OFF_CROW + (size_t)BB*CAP*8*4;      // float[4][4096][8]
static const size_t OFF_SEL  = OFF_NBOX + (size_t)BB*CAP*8*4;      // int[4][1000] (padded 16K)
static const size_t OFF_MASK = OFF_SEL + 16384;            // u64[4][64][4000] col-major = 8 MB

// ---- radix histogram pass (8 bits per pass, MSB first) ----
__global__ void k_hist(const float* __restrict__ obj, u32* __restrict__ mono,
                       u32* __restrict__ hist, const u32* __restrict__ pfx, int pass) {
  __shared__ u32 lh[256];
  lh[threadIdx.x] = 0;
  __syncthreads();
  size_t base = (size_t)blockIdx.x * 1024;   // 1024 items per block, never crosses a batch
  int b = (int)(base >> 18);
  u32 p = pass ? pfx[b] : 0u;
  for (int k = 0; k < 4; ++k) {
    size_t g = base + threadIdx.x + (size_t)k*256;
    u32 m;
    if (pass == 0) {
      float x = obj[g];
      float e = (float)exp(-(double)x);      // correctly-rounded f32 exp
      float s = 1.0f / (1.0f + e);           // f32 sigmoid pipeline
      m = __float_as_uint(s);                // scores in (0,1): bits order == value order
      mono[g] = m;
    } else {
      m = mono[g];
    }
    u32 bin; bool ok;
    if (pass == 0)      { ok = true;            bin = m >> 24; }
    else if (pass == 1) { ok = (m >> 24) == p;  bin = (m >> 16) & 255u; }
    else if (pass == 2) { ok = (m >> 16) == p;  bin = (m >> 8)  & 255u; }
    else                { ok = (m >> 8)  == p;  bin = m & 255u; }
    if (ok) atomicAdd(&lh[bin], 1u);
  }
  __syncthreads();
  u32 v = lh[threadIdx.x];
  if (v) atomicAdd(&hist[((size_t)pass*BB + b)*256 + threadIdx.x], v);
}

__global__ void k_resolve(const u32* __restrict__ hist, u32* __restrict__ pfx,
                          int* __restrict__ need, int pass) {
  int b = threadIdx.x;
  if (b >= BB) return;
  u32 p = pass ? pfx[b] : 0u;
  int nd = pass ? need[b] : PRE;
  const u32* h = hist + ((size_t)pass*BB + b)*256;
  u32 acc = 0; int chosen = 0;
  for (int bin = 255; bin >= 0; --bin) {
    u32 c = h[bin];
    if (acc + c >= (u32)nd) { chosen = bin; nd -= (int)acc; break; }
    acc += c;
  }
  pfx[b] = (p << 8) | (u32)chosen;   // after pass 3: full 32-bit value of the 4000th score
  need[b] = nd;                      // after pass 3: how many ties at V belong in top-4000
}

// ---- compact candidates: LDS-staged, one global atomic per block per class ----
__global__ __launch_bounds__(256) void k_compact(const u32* __restrict__ mono,
                                                 const u32* __restrict__ pfx,
                                                 int* __restrict__ cntG,
                                                 int* __restrict__ cntE,
                                                 u64* __restrict__ keys) {
  __shared__ u64 st[4096];            // G from front, ties from back
  __shared__ int nG, nE, baseG, baseE;
  int tid = threadIdx.x;
  if (tid == 0) { nG = 0; nE = 0; }
  __syncthreads();
  size_t blockBase = (size_t)blockIdx.x * 4096;
  int b = (int)(blockBase >> 18);
  u32 V = pfx[b];
  for (int k = 0; k < 16; ++k) {
    size_t g = blockBase + (size_t)k*256 + tid;
    u32 m = mono[g];
    if (m >= V) {
      u64 key = ((u64)(~m) << 32) | (u64)(g & (AA - 1));
      if (m > V) { int p = atomicAdd(&nG, 1); st[p] = key; }
      else       { int p = atomicAdd(&nE, 1); if (p < 512) st[4095 - p] = key; }
    }
  }
  __syncthreads();
  int ne = nE < 512 ? nE : 512;
  if (tid == 0) baseG = atomicAdd(&cntG[b*32], nG);
  if (tid == 1) baseE = atomicAdd(&cntE[b*32], ne);
  __syncthreads();
  for (int i = tid; i < nG; i += 256) {
    int p = baseG + i;
    if (p < CAP) keys[(size_t)b*CAP + p] = st[i];
  }
  for (int i = tid; i < ne; i += 256) {
    int slot = CAP - 1 - (baseE + i);
    if (slot >= 0) keys[(size_t)b*CAP + slot] = st[4095 - i];
  }
}

// ---- bitonic sort 4096 keys per batch: (score desc, idx asc) == lax.top_k order ----
__global__ __launch_bounds__(1024) void k_sort(const u64* __restrict__ keys,
                                               int* __restrict__ sidx,
                                               float* __restrict__ ssc) {
  __shared__ u64 sk[CAP];
  int b = blockIdx.x;
  for (int t = threadIdx.x; t < CAP; t += 1024) sk[t] = keys[(size_t)b*CAP + t];
  __syncthreads();
  for (int k = 2; k <= CAP; k <<= 1) {
    for (int j = k >> 1; j > 0; j >>= 1) {
      for (int t = threadIdx.x; t < CAP/2; t += 1024) {
        int i = ((t / j) * 2 * j) + (t & (j - 1));
        int x = i | j;
        u64 a = sk[i], c = sk[x];
        bool up = ((i & k) == 0);
        if ((a > c) == up) { sk[i] = c; sk[x] = a; }
      }
      __syncthreads();
    }
  }
  for (int t = threadIdx.x; t < PRE; t += 1024) {
    u64 kk = sk[t];
    sidx[b*CAP + t] = (int)(kk & 0xFFFFFFFFull);
    u32 m = ~(u32)(kk >> 32);
    ssc[b*CAP + t] = __uint_as_float(m);
  }
}

// ---- decode top-4000 boxes + precompute augmented lo/hi/vol for IoU ----
__global__ void k_decode(const float* __restrict__ reg, const float* __restrict__ anc,
                         const int* __restrict__ sidx, const float* __restrict__ ssc,
                         float* __restrict__ crow, float* __restrict__ nbox) {
  int t = blockIdx.x*256 + threadIdx.x;
  if (t >= BB*PRE) return;
  int b = t / PRE, i = t - b*PRE;
  int idx = sidx[b*CAP + i];
  size_t g = ((size_t)b << 18) + (size_t)idx;
  const float* rg = reg + g*7;
  const float* an = anc + g*7;
  float xa=an[0], ya=an[1], za=an[2], wa=an[3], la=an[4], ha=an[5], ra=an[6];
  float dx=rg[0], dy=rg[1], dz=rg[2], dw=rg[3], dl=rg[4], dh=rg[5], dr=rg[6];
  float diag = sqrtf(wa*wa + la*la);
  float x = dx*diag + xa;
  float y = dy*diag + ya;
  float z = dz*ha + za;
  float w = expf(dw)*wa;
  float l = expf(dl)*la;
  float h = expf(dh)*ha;
  float r = dr + ra;
  float* cr = crow + ((size_t)b*CAP + i)*8;
  cr[0]=x; cr[1]=y; cr[2]=z; cr[3]=w; cr[4]=l; cr[5]=h; cr[6]=r; cr[7]=ssc[b*CAP + i];
  float sx = fmaxf(w, 0.2f), sy = fmaxf(l, 0.2f), sz = fmaxf(h, 0.2f);
  float* nb = nbox + ((size_t)b*CAP + i)*8;
  nb[0]=x - sx*0.5f; nb[1]=y - sy*0.5f; nb[2]=z;
  nb[3]=x + sx*0.5f; nb[4]=y + sy*0.5f; nb[5]=z + sz;
  nb[6]=sx*sy*sz;   nb[7]=0.f;
}

// ---- suppression bitmask, col-major mask[b][word c][row i] ----
// 256-row x 64-col tiles; consecutive threads = consecutive rows -> coalesced
// u64 stores (R3 row-major layout had 512B-strided stores: 16.5MB WRITE_SIZE
// for 4.2MB of words). Branch-free inner loop; diagonal/col-validity applied
// as end masks; divide replaced by inter > 0.3*uni (union >= 0.008 >> 1e-8).
__global__ __launch_bounds__(256) void k_mask(const float* __restrict__ nbox,
                                              u64* __restrict__ mask) {
  int c = blockIdx.x;            // word/column block 0..62
  int R = blockIdx.y;            // 256-row tile 0..15
  int b = blockIdx.z;
  if (c < R*4) return;           // tile fully below diagonal: words never read
  __shared__ float4 ca4[64], cb4[64];
  int t = threadIdx.x;
  int j0 = c*64;
  if (t < 64) {
    int j = j0 + t; int jc = j < PRE ? j : 0;
    const float4* p = (const float4*)(nbox + ((size_t)b*CAP + jc)*8);
    ca4[t] = p[0]; cb4[t] = p[1];
  }
  __syncthreads();
  int i = R*256 + t;
  if (i >= PRE) return;
  const float4* rp = (const float4*)(nbox + ((size_t)b*CAP + i)*8);
  float4 A = rp[0], Bv = rp[1];  // A = lo.xyz, hi.x ; Bv = hi.y, hi.z, vol, pad
  u64 bits = 0;
  #pragma unroll
  for (int jj = 0; jj < 64; ++jj) {
    float4 C = ca4[jj], D = cb4[jj];
    float d0 = fminf(A.w,  C.w) - fmaxf(A.x, C.x);
    float d1 = fminf(Bv.x, D.x) - fmaxf(A.y, C.y);
    float d2 = fminf(Bv.y, D.y) - fmaxf(A.z, C.z);
    float inter = fmaxf(d0, 0.f) * fmaxf(d1, 0.f) * fmaxf(d2, 0.f);
    float uni = Bv.z + D.z - inter;
    if (inter > 0.3f * uni) bits |= (1ull << jj);
  }
  int vcols = PRE - j0;                                  // >= 32 for c <= 62
  if (vcols < 64) bits &= ((1ull << vcols) - 1ull);      // clear cols >= PRE
  if (j0 <= i) {                                          // clear cols j <= i
    int d = i - j0;
    if (d >= 63) bits = 0;
    else bits &= ~((2ull << d) - 1ull);
  }
  mask[((size_t)b*MASKW + c)*PRE + i] = bits;
}

// ---- block-sequential greedy NMS reduce, double-buffered prefetch ----
__device__ __forceinline__ void load_blk(u64 (&buf)[64], const u64* col, int q, int lane) {
  #pragma unroll
  for (int jj = 0; jj < 64; ++jj) {
    int row = q*64 + jj;
    u64 v = 0;
    if (q < NBLK && lane >= q && row < PRE) v = col[row];
    buf[jj] = v;
  }
}

__device__ __forceinline__ void resolve_blk(u64 (&buf)[64], int q, int lane,
                                            u64& removed, int& kc,
                                            int* __restrict__ sel, int b) {
  int nv = PRE - q*64; if (nv > 64) nv = 64;
  u64 cur = removed, km = 0;
  #pragma unroll
  for (int jj = 0; jj < 64; ++jj) {
    if (((cur >> jj) & 1ull) == 0ull) { km |= (1ull << jj); cur |= buf[jj]; }
  }
  u64 kmw = __shfl(km, q, 64);
  if (nv < 64) kmw &= ((1ull << nv) - 1ull);
  #pragma unroll
  for (int jj = 0; jj < 64; ++jj) {
    if ((kmw >> jj) & 1ull) removed |= buf[jj];
  }
  bool mine = (kmw >> lane) & 1ull;
  int pos = kc + (int)__popcll(kmw & ((1ull << lane) - 1ull));
  if (mine && pos < POST) sel[b*POST + pos] = q*64 + lane;
  kc += (int)__popcll(kmw);
}

__global__ __launch_bounds__(64) void k_reduce(const u64* __restrict__ mask,
                                               int* __restrict__ sel,
                                               int* __restrict__ kept) {
  int b = blockIdx.x, lane = threadIdx.x;
  const u64* col = mask + ((size_t)b*MASKW + lane)*PRE;   // this lane's word-column
  u64 bufA[64], bufB[64];
  u64 removed = 0;
  int kc = 0;
  load_blk(bufA, col, 0, lane);
  for (int q0 = 0; q0 < NBLK; q0 += 2) {
    load_blk(bufB, col, q0+1, lane);                      // prefetch next block
    resolve_blk(bufA, q0, lane, removed, kc, sel, b);
    if (kc >= POST) break;
    if (q0+1 >= NBLK) break;
    load_blk(bufA, col, q0+2, lane);                      // prefetch next-next
    resolve_blk(bufB, q0+1, lane, removed, kc, sel, b);
    if (kc >= POST) break;
  }
  if (lane == 0) kept[b] = kc < POST ? kc : POST;
}

// ---- gather output rows; zero-fill invalid ranks (matches boxes[sel]*valid) ----
__global__ void k_out(const float* __restrict__ crow, const int* __restrict__ sel,
                      const int* __restrict__ kept, float* __restrict__ out) {
  int t = blockIdx.x*256 + threadIdx.x;
  if (t >= BB*POST) return;
  int b = t / POST, r = t - b*POST;
  float4 o0 = make_float4(0.f,0.f,0.f,0.f), o1 = o0;
  if (r < kept[b]) {
    int i = sel[b*POST + r];
    const float4* p = (const float4*)(crow + ((size_t)b*CAP + i)*8);
    o0 = p[0]; o1 = p[1];
  }
  float4* q = (float4*)(out + (size_t)t*8);
  q[0] = o0; q[1] = o1;
}

extern "C" void kernel_launch(void* const* d_in, const int* in_sizes, int n_in,
                              void* d_out, int out_size, void* d_ws, size_t ws_size,
                              hipStream_t stream) {
  const float* obj = (const float*)d_in[0];   // (N,)
  const float* reg = (const float*)d_in[1];   // (N,7)
  const float* anc = (const float*)d_in[2];   // (N,7)
  float* out = (float*)d_out;                 // (4,1000,8)
  char* ws = (char*)d_ws;

  u32*  hist = (u32*)(ws + OFF_HIST);
  u32*  pfx  = (u32*)(ws + OFF_PFX);
  int*  need = (int*)(ws + OFF_NEED);
  int*  kept = (int*)(ws + OFF_KEPT);
  int*  cntG = (int*)(ws + OFF_CNTG);
  int*  cntE = (int*)(ws + OFF_CNTE);
  u32*  mono = (u32*)(ws + OFF_MONO);
  u64*  keys = (u64*)(ws + OFF_KEYS);
  int*  sidx = (int*)(ws + OFF_SIDX);
  float* ssc = (float*)(ws + OFF_SSC);
  float* crow = (float*)(ws + OFF_CROW);
  float* nbox = (float*)(ws + OFF_NBOX);
  int*  sel  = (int*)(ws + OFF_SEL);
  u64*  mask = (u64*)(ws + OFF_MASK);

  hipMemsetAsync(ws, 0, CTRL_END, stream);                        // hists + counters
  hipMemsetAsync(ws + OFF_KEYS, 0xFF, (size_t)BB*CAP*8, stream);  // key padding sorts last

  for (int pass = 0; pass < 4; ++pass) {
    k_hist<<<NN/1024, 256, 0, stream>>>(obj, mono, hist, pfx, pass);
    k_resolve<<<1, 64, 0, stream>>>(hist, pfx, need, pass);
  }
  k_compact<<<NN/4096, 256, 0, stream>>>(mono, pfx, cntG, cntE, keys);
  k_sort<<<BB, 1024, 0, stream>>>(keys, sidx, ssc);
  k_decode<<<(BB*PRE + 255)/256, 256, 0, stream>>>(reg, anc, sidx, ssc, crow, nbox);
  k_mask<<<dim3(NBLK, 16, BB), 256, 0, stream>>>(nbox, mask);
  k_reduce<<<BB, 64, 0, stream>>>(mask, sel, kept);
  k_out<<<(BB*POST + 255)/256, 256, 0, stream>>>(crow, sel, kept, out);
}

// Round 5
// 314.501 us; speedup vs baseline: 2.4936x; 2.4936x over previous
//
#include <hip/hip_runtime.h>
#include <math.h>

typedef unsigned int u32;
typedef unsigned long long u64;

#define BB 4
#define AA 262144              // 1<<18
#define NN (BB*AA)
#define PRE 4000
#define POST 1000
#define CAP 4096
#define MASKW 64
#define NBLK 63                // ceil(4000/64)

// ---- workspace layout (bytes) ----
static const size_t OFF_HIST = 0;                          // 4*4*256*4 = 16384
static const size_t OFF_PFX  = 16384;                      // u32[4]
static const size_t OFF_NEED = 16448;                      // int[4]
static const size_t OFF_KEPT = 16512;                      // int[4]
static const size_t OFF_CNTG = 16640;                      // int, stride 32 ints (128B) x4
static const size_t OFF_CNTE = 17152;                      // int, stride 32 ints (128B) x4
static const size_t CTRL_END = 17664;
static const size_t OFF_MONO = 17664;                              // u32[NN] = 4 MiB
static const size_t OFF_KEYS = OFF_MONO + (size_t)NN*4;            // u64[4][4096]
static const size_t OFF_SIDX = OFF_KEYS + (size_t)BB*CAP*8;        // int[4][4096]
static const size_t OFF_SSC  = OFF_SIDX + (size_t)BB*CAP*4;        // float[4][4096]
static const size_t OFF_CROW = OFF_SSC  + (size_t)BB*CAP*4;        // float[4][4096][8]
static const size_t OFF_NBOX = OFF_CROW + (size_t)BB*CAP*8*4;      // float[4][4096][8]
static const size_t OFF_SEL  = OFF_NBOX + (size_t)BB*CAP*8*4;      // int[4][1000] (padded 16K)
static const size_t OFF_MASK = OFF_SEL + 16384;            // u64[4][64][4000] col-major = 8 MB

// ---- radix histogram pass (8 bits per pass, MSB first) ----
__global__ void k_hist(const float* __restrict__ obj, u32* __restrict__ mono,
                       u32* __restrict__ hist, const u32* __restrict__ pfx, int pass) {
  __shared__ u32 lh[256];
  lh[threadIdx.x] = 0;
  __syncthreads();
  size_t base = (size_t)blockIdx.x * 1024;   // 1024 items per block, never crosses a batch
  int b = (int)(base >> 18);
  u32 p = pass ? pfx[b] : 0u;
  for (int k = 0; k < 4; ++k) {
    size_t g = base + threadIdx.x + (size_t)k*256;
    u32 m;
    if (pass == 0) {
      float x = obj[g];
      float e = (float)exp(-(double)x);      // correctly-rounded f32 exp
      float s = 1.0f / (1.0f + e);           // f32 sigmoid pipeline
      m = __float_as_uint(s);                // scores in (0,1): bits order == value order
      mono[g] = m;
    } else {
      m = mono[g];
    }
    u32 bin; bool ok;
    if (pass == 0)      { ok = true;            bin = m >> 24; }
    else if (pass == 1) { ok = (m >> 24) == p;  bin = (m >> 16) & 255u; }
    else if (pass == 2) { ok = (m >> 16) == p;  bin = (m >> 8)  & 255u; }
    else                { ok = (m >> 8)  == p;  bin = m & 255u; }
    if (ok) atomicAdd(&lh[bin], 1u);
  }
  __syncthreads();
  u32 v = lh[threadIdx.x];
  if (v) atomicAdd(&hist[((size_t)pass*BB + b)*256 + threadIdx.x], v);
}

__global__ void k_resolve(const u32* __restrict__ hist, u32* __restrict__ pfx,
                          int* __restrict__ need, int pass) {
  int b = threadIdx.x;
  if (b >= BB) return;
  u32 p = pass ? pfx[b] : 0u;
  int nd = pass ? need[b] : PRE;
  const u32* h = hist + ((size_t)pass*BB + b)*256;
  u32 acc = 0; int chosen = 0;
  for (int bin = 255; bin >= 0; --bin) {
    u32 c = h[bin];
    if (acc + c >= (u32)nd) { chosen = bin; nd -= (int)acc; break; }
    acc += c;
  }
  pfx[b] = (p << 8) | (u32)chosen;   // after pass 3: full 32-bit value of the 4000th score
  need[b] = nd;                      // after pass 3: how many ties at V belong in top-4000
}

// ---- compact candidates: LDS-staged, one global atomic per block per class ----
__global__ __launch_bounds__(256) void k_compact(const u32* __restrict__ mono,
                                                 const u32* __restrict__ pfx,
                                                 int* __restrict__ cntG,
                                                 int* __restrict__ cntE,
                                                 u64* __restrict__ keys) {
  __shared__ u64 st[4096];            // G from front, ties from back
  __shared__ int nG, nE, baseG, baseE;
  int tid = threadIdx.x;
  if (tid == 0) { nG = 0; nE = 0; }
  __syncthreads();
  size_t blockBase = (size_t)blockIdx.x * 4096;
  int b = (int)(blockBase >> 18);
  u32 V = pfx[b];
  for (int k = 0; k < 16; ++k) {
    size_t g = blockBase + (size_t)k*256 + tid;
    u32 m = mono[g];
    if (m >= V) {
      u64 key = ((u64)(~m) << 32) | (u64)(g & (AA - 1));
      if (m > V) { int p = atomicAdd(&nG, 1); st[p] = key; }
      else       { int p = atomicAdd(&nE, 1); if (p < 512) st[4095 - p] = key; }
    }
  }
  __syncthreads();
  int ne = nE < 512 ? nE : 512;
  if (tid == 0) baseG = atomicAdd(&cntG[b*32], nG);
  if (tid == 1) baseE = atomicAdd(&cntE[b*32], ne);
  __syncthreads();
  for (int i = tid; i < nG; i += 256) {
    int p = baseG + i;
    if (p < CAP) keys[(size_t)b*CAP + p] = st[i];
  }
  for (int i = tid; i < ne; i += 256) {
    int slot = CAP - 1 - (baseE + i);
    if (slot >= 0) keys[(size_t)b*CAP + slot] = st[4095 - i];
  }
}

// ---- bitonic sort 4096 keys per batch: (score desc, idx asc) == lax.top_k order ----
__global__ __launch_bounds__(1024) void k_sort(const u64* __restrict__ keys,
                                               int* __restrict__ sidx,
                                               float* __restrict__ ssc) {
  __shared__ u64 sk[CAP];
  int b = blockIdx.x;
  for (int t = threadIdx.x; t < CAP; t += 1024) sk[t] = keys[(size_t)b*CAP + t];
  __syncthreads();
  for (int k = 2; k <= CAP; k <<= 1) {
    for (int j = k >> 1; j > 0; j >>= 1) {
      for (int t = threadIdx.x; t < CAP/2; t += 1024) {
        int i = ((t / j) * 2 * j) + (t & (j - 1));
        int x = i | j;
        u64 a = sk[i], c = sk[x];
        bool up = ((i & k) == 0);
        if ((a > c) == up) { sk[i] = c; sk[x] = a; }
      }
      __syncthreads();
    }
  }
  for (int t = threadIdx.x; t < PRE; t += 1024) {
    u64 kk = sk[t];
    sidx[b*CAP + t] = (int)(kk & 0xFFFFFFFFull);
    u32 m = ~(u32)(kk >> 32);
    ssc[b*CAP + t] = __uint_as_float(m);
  }
}

// ---- decode top-4000 boxes + precompute augmented lo/hi/vol for IoU ----
__global__ void k_decode(const float* __restrict__ reg, const float* __restrict__ anc,
                         const int* __restrict__ sidx, const float* __restrict__ ssc,
                         float* __restrict__ crow, float* __restrict__ nbox) {
  int t = blockIdx.x*256 + threadIdx.x;
  if (t >= BB*PRE) return;
  int b = t / PRE, i = t - b*PRE;
  int idx = sidx[b*CAP + i];
  size_t g = ((size_t)b << 18) + (size_t)idx;
  const float* rg = reg + g*7;
  const float* an = anc + g*7;
  float xa=an[0], ya=an[1], za=an[2], wa=an[3], la=an[4], ha=an[5], ra=an[6];
  float dx=rg[0], dy=rg[1], dz=rg[2], dw=rg[3], dl=rg[4], dh=rg[5], dr=rg[6];
  float diag = sqrtf(wa*wa + la*la);
  float x = dx*diag + xa;
  float y = dy*diag + ya;
  float z = dz*ha + za;
  float w = expf(dw)*wa;
  float l = expf(dl)*la;
  float h = expf(dh)*ha;
  float r = dr + ra;
  float* cr = crow + ((size_t)b*CAP + i)*8;
  cr[0]=x; cr[1]=y; cr[2]=z; cr[3]=w; cr[4]=l; cr[5]=h; cr[6]=r; cr[7]=ssc[b*CAP + i];
  float sx = fmaxf(w, 0.2f), sy = fmaxf(l, 0.2f), sz = fmaxf(h, 0.2f);
  float* nb = nbox + ((size_t)b*CAP + i)*8;
  nb[0]=x - sx*0.5f; nb[1]=y - sy*0.5f; nb[2]=z;
  nb[3]=x + sx*0.5f; nb[4]=y + sy*0.5f; nb[5]=z + sz;
  nb[6]=sx*sy*sz;   nb[7]=0.f;
}

// ---- suppression bitmask, col-major mask[b][word c][row i] ----
__global__ __launch_bounds__(256) void k_mask(const float* __restrict__ nbox,
                                              u64* __restrict__ mask) {
  int c = blockIdx.x;            // word/column block 0..62
  int R = blockIdx.y;            // 256-row tile 0..15
  int b = blockIdx.z;
  if (c < R*4) return;           // tile fully below diagonal: words never read
  __shared__ float4 ca4[64], cb4[64];
  int t = threadIdx.x;
  int j0 = c*64;
  if (t < 64) {
    int j = j0 + t; int jc = j < PRE ? j : 0;
    const float4* p = (const float4*)(nbox + ((size_t)b*CAP + jc)*8);
    ca4[t] = p[0]; cb4[t] = p[1];
  }
  __syncthreads();
  int i = R*256 + t;
  if (i >= PRE) return;
  const float4* rp = (const float4*)(nbox + ((size_t)b*CAP + i)*8);
  float4 A = rp[0], Bv = rp[1];  // A = lo.xyz, hi.x ; Bv = hi.y, hi.z, vol, pad
  u64 bits = 0;
  #pragma unroll
  for (int jj = 0; jj < 64; ++jj) {
    float4 C = ca4[jj], D = cb4[jj];
    float d0 = fminf(A.w,  C.w) - fmaxf(A.x, C.x);
    float d1 = fminf(Bv.x, D.x) - fmaxf(A.y, C.y);
    float d2 = fminf(Bv.y, D.y) - fmaxf(A.z, C.z);
    float inter = fmaxf(d0, 0.f) * fmaxf(d1, 0.f) * fmaxf(d2, 0.f);
    float uni = Bv.z + D.z - inter;
    if (inter > 0.3f * uni) bits |= (1ull << jj);
  }
  int vcols = PRE - j0;                                  // >= 32 for c <= 62
  if (vcols < 64) bits &= ((1ull << vcols) - 1ull);      // clear cols >= PRE
  if (j0 <= i) {                                          // clear cols j <= i
    int d = i - j0;
    if (d >= 63) bits = 0;
    else bits &= ~((2ull << d) - 1ull);
  }
  mask[((size_t)b*MASKW + c)*PRE + i] = bits;
}

// ---- block-sequential greedy NMS reduce: one wave per batch, SINGLE buffer ----
// R4's double-buffer (bufA+bufB = 256 VGPRs) hit the 256-VGPR allocation cap
// and spilled both buffers to scratch (VGPR_Count=256, 512 us). Single 64-u64
// buffer (~150 VGPR total) + ulonglong2 column loads; col-major layout keeps
// each lane's block read contiguous (512 B).
__global__ __launch_bounds__(64) void k_reduce(const u64* __restrict__ mask,
                                               int* __restrict__ sel,
                                               int* __restrict__ kept) {
  int b = blockIdx.x, lane = threadIdx.x;
  const u64* col = mask + ((size_t)b*MASKW + lane)*PRE;   // this lane's word-column
  u64 removed = 0;
  int kc = 0;
  for (int q = 0; q < NBLK; ++q) {
    u64 buf[64];
    bool act = lane >= q;        // words < q of these rows were never written
    if (q < NBLK - 1) {          // rows q*64 .. q*64+63 all < PRE
      const ulonglong2* p = (const ulonglong2*)(col + q*64);
      #pragma unroll
      for (int jj = 0; jj < 32; ++jj) {
        ulonglong2 v; v.x = 0; v.y = 0;
        if (act) v = p[jj];
        buf[2*jj] = v.x; buf[2*jj+1] = v.y;
      }
    } else {                     // last block: guard rows >= PRE
      #pragma unroll
      for (int jj = 0; jj < 64; ++jj) {
        int row = q*64 + jj;
        u64 v = 0;
        if (act && row < PRE) v = col[row];
        buf[jj] = v;
      }
    }
    int nv = PRE - q*64; if (nv > 64) nv = 64;
    u64 cur = removed, km = 0;
    #pragma unroll
    for (int jj = 0; jj < 64; ++jj) {
      if (((cur >> jj) & 1ull) == 0ull) { km |= (1ull << jj); cur |= buf[jj]; }
    }
    u64 kmw = __shfl(km, q, 64);
    if (nv < 64) kmw &= ((1ull << nv) - 1ull);
    #pragma unroll
    for (int jj = 0; jj < 64; ++jj) {
      if ((kmw >> jj) & 1ull) removed |= buf[jj];
    }
    bool mine = (kmw >> lane) & 1ull;
    int pos = kc + (int)__popcll(kmw & ((1ull << lane) - 1ull));
    if (mine && pos < POST) sel[b*POST + pos] = q*64 + lane;
    kc += (int)__popcll(kmw);
    if (kc >= POST) break;
  }
  if (lane == 0) kept[b] = kc < POST ? kc : POST;
}

// ---- gather output rows; zero-fill invalid ranks (matches boxes[sel]*valid) ----
__global__ void k_out(const float* __restrict__ crow, const int* __restrict__ sel,
                      const int* __restrict__ kept, float* __restrict__ out) {
  int t = blockIdx.x*256 + threadIdx.x;
  if (t >= BB*POST) return;
  int b = t / POST, r = t - b*POST;
  float4 o0 = make_float4(0.f,0.f,0.f,0.f), o1 = o0;
  if (r < kept[b]) {
    int i = sel[b*POST + r];
    const float4* p = (const float4*)(crow + ((size_t)b*CAP + i)*8);
    o0 = p[0]; o1 = p[1];
  }
  float4* q = (float4*)(out + (size_t)t*8);
  q[0] = o0; q[1] = o1;
}

extern "C" void kernel_launch(void* const* d_in, const int* in_sizes, int n_in,
                              void* d_out, int out_size, void* d_ws, size_t ws_size,
                              hipStream_t stream) {
  const float* obj = (const float*)d_in[0];   // (N,)
  const float* reg = (const float*)d_in[1];   // (N,7)
  const float* anc = (const float*)d_in[2];   // (N,7)
  float* out = (float*)d_out;                 // (4,1000,8)
  char* ws = (char*)d_ws;

  u32*  hist = (u32*)(ws + OFF_HIST);
  u32*  pfx  = (u32*)(ws + OFF_PFX);
  int*  need = (int*)(ws + OFF_NEED);
  int*  kept = (int*)(ws + OFF_KEPT);
  int*  cntG = (int*)(ws + OFF_CNTG);
  int*  cntE = (int*)(ws + OFF_CNTE);
  u32*  mono = (u32*)(ws + OFF_MONO);
  u64*  keys = (u64*)(ws + OFF_KEYS);
  int*  sidx = (int*)(ws + OFF_SIDX);
  float* ssc = (float*)(ws + OFF_SSC);
  float* crow = (float*)(ws + OFF_CROW);
  float* nbox = (float*)(ws + OFF_NBOX);
  int*  sel  = (int*)(ws + OFF_SEL);
  u64*  mask = (u64*)(ws + OFF_MASK);

  hipMemsetAsync(ws, 0, CTRL_END, stream);                        // hists + counters
  hipMemsetAsync(ws + OFF_KEYS, 0xFF, (size_t)BB*CAP*8, stream);  // key padding sorts last

  for (int pass = 0; pass < 4; ++pass) {
    k_hist<<<NN/1024, 256, 0, stream>>>(obj, mono, hist, pfx, pass);
    k_resolve<<<1, 64, 0, stream>>>(hist, pfx, need, pass);
  }
  k_compact<<<NN/4096, 256, 0, stream>>>(mono, pfx, cntG, cntE, keys);
  k_sort<<<BB, 1024, 0, stream>>>(keys, sidx, ssc);
  k_decode<<<(BB*PRE + 255)/256, 256, 0, stream>>>(reg, anc, sidx, ssc, crow, nbox);
  k_mask<<<dim3(NBLK, 16, BB), 256, 0, stream>>>(nbox, mask);
  k_reduce<<<BB, 64, 0, stream>>>(mask, sel, kept);
  k_out<<<(BB*POST + 255)/256, 256, 0, stream>>>(crow, sel, kept, out);
}